// Round 4
// baseline (21.031 us; speedup 1.0000x reference)
//
#include <hip/hip_runtime.h>

// IntensityTransform: out[b,h,w,c] = it[b, clip(rint(255*im[b,h,w,c]),0,255), c]
// im: [16,512,512,3] f32, it: [16,256,3] f32, out: [16,512,512,3] f32.
// ~100.7 MB mandatory traffic. 6.3 TB/s stream ceiling -> 16.0 us kernel floor.
//
// Round 4: remove nontemporal stores (they forbid L3 write absorption across
// graph replays; working set 101 MB < 256 MB Infinity Cache). Clamp in float
// domain (v_med3_f32) before rndne+cvt; incremental mod-3 channel tracking.
// Pre-committed: unchanged dur => overhead + HBM ceiling => roofline.

#define NB 16
#define HW (512 * 512)
#define NC 3
#define NI 256
#define ELEMS_PER_BATCH (HW * NC)            // 786432
#define VEC4_PER_BATCH (ELEMS_PER_BATCH / 4) // 196608
#define BLOCKS_PER_BATCH 128
#define THREADS 256
#define VPT 6  // float4s per thread: 196608 / (128*256) = 6 exactly
#define VSTRIDE (BLOCKS_PER_BATCH * THREADS) // 32768; 32768 % 3 == 2

typedef float f32x4 __attribute__((ext_vector_type(4)));

__global__ __launch_bounds__(THREADS) void intensity_lut_kernel(
    const float* __restrict__ im,
    const float* __restrict__ it,
    float* __restrict__ out)
{
    __shared__ float lut[NI * NC];  // 3 KB per block

    const int b = blockIdx.y;

    // Stage this batch's LUT into LDS (768 floats).
    const float* itb = it + (size_t)b * (NI * NC);
    for (int i = threadIdx.x; i < NI * NC; i += THREADS) lut[i] = itb[i];
    __syncthreads();

    const f32x4* __restrict__ im4  = (const f32x4*)(im  + (size_t)b * ELEMS_PER_BATCH);
    f32x4* __restrict__       out4 = (f32x4*)      (out + (size_t)b * ELEMS_PER_BATCH);

    const int v0 = blockIdx.x * THREADS + threadIdx.x;

    // Issue all 6 global loads first (compile-time indices -> registers, 6 in flight).
    f32x4 x[VPT];
#pragma unroll
    for (int k = 0; k < VPT; ++k) x[k] = im4[v0 + k * VSTRIDE];

    // channel of element 4*v: 4 % 3 == 1 -> c0 = v % 3; VSTRIDE % 3 == 2
    int c0 = v0 % 3;

#pragma unroll
    for (int k = 0; k < VPT; ++k) {
        const int v = v0 + k * VSTRIDE;

        int c1 = c0 + 1; if (c1 == 3) c1 = 0;
        int c2 = c1 + 1; if (c2 == 3) c2 = 0;

        // clamp in float (v_med3_f32), then RNE round (rintf = np.round), then cvt.
        // Equivalent to round-then-clip since rint is monotonic and fixes [0,255].
        int i0 = (int)rintf(fminf(fmaxf(255.0f * x[k].x, 0.0f), 255.0f));
        int i1 = (int)rintf(fminf(fmaxf(255.0f * x[k].y, 0.0f), 255.0f));
        int i2 = (int)rintf(fminf(fmaxf(255.0f * x[k].z, 0.0f), 255.0f));
        int i3 = (int)rintf(fminf(fmaxf(255.0f * x[k].w, 0.0f), 255.0f));

        f32x4 y;
        y.x = lut[i0 * NC + c0];
        y.y = lut[i1 * NC + c1];
        y.z = lut[i2 * NC + c2];
        y.w = lut[i3 * NC + c0];

        out4[v] = y;

        // v += VSTRIDE => c0 = (c0 + 2) % 3 = c0 - 1 mod 3
        c0 = (c0 == 0) ? 2 : c0 - 1;
    }
}

extern "C" void kernel_launch(void* const* d_in, const int* in_sizes, int n_in,
                              void* d_out, int out_size, void* d_ws, size_t ws_size,
                              hipStream_t stream) {
    const float* im = (const float*)d_in[0];
    const float* it = (const float*)d_in[1];
    float* out = (float*)d_out;

    dim3 grid(BLOCKS_PER_BATCH, NB);
    intensity_lut_kernel<<<grid, THREADS, 0, stream>>>(im, it, out);
}